// Round 2
// baseline (355.268 us; speedup 1.0000x reference)
//
#include <hip/hip_runtime.h>
#include <math.h>

#define NB_CLASSES 1024
#define SZ_EMBED 128
#define N_SAMPLES 262144
#define MTILE 64
#define CTILE 64
#define XSTRIDE 136  // bf16 elems; 272B row stride = 68 dwords, 68%32=4 -> 2-way bank alias (free)

typedef __bf16 v8bf __attribute__((ext_vector_type(8)));
typedef float v4f __attribute__((ext_vector_type(4)));

// exp(+-32*cos + 3.2) = exp2(46.166...*(+-cos) + 4.6166...)
#define EXP_A 46.16624130844683f
#define EXP_B 4.616624130844683f

__device__ __forceinline__ unsigned short f2bf(float f) {
    union { float f; unsigned u; } v; v.f = f;
    unsigned u = v.u;
    unsigned rounding = 0x7FFFu + ((u >> 16) & 1u);
    return (unsigned short)((u + rounding) >> 16);
}

__global__ __launch_bounds__(256) void norm_proxies_kernel(
    const float* __restrict__ proxies, unsigned short* __restrict__ pn) {
    int wv = threadIdx.x >> 6;
    int lane = threadIdx.x & 63;
    int row = blockIdx.x * 4 + wv;  // grid = 256 -> rows 0..1023
    const float* src = proxies + (size_t)row * SZ_EMBED + lane * 2;
    float2 x = *(const float2*)src;
    float ss = x.x * x.x + x.y * x.y;
    #pragma unroll
    for (int off = 32; off; off >>= 1) ss += __shfl_xor(ss, off);
    float inv = rsqrtf(ss + 1e-12f);
    unsigned pk = (unsigned)f2bf(x.x * inv) | ((unsigned)f2bf(x.y * inv) << 16);
    *(unsigned*)(pn + (size_t)row * SZ_EMBED + lane * 2) = pk;
}

__global__ __launch_bounds__(256) void main_kernel(
    const float* __restrict__ X, const int* __restrict__ T,
    const unsigned short* __restrict__ Pn,
    float* __restrict__ pos_sum, float* __restrict__ neg_sum) {
    __shared__ unsigned short xtile[MTILE * XSTRIDE];
    __shared__ unsigned short ptile[CTILE * XSTRIDE];
    __shared__ float psum[MTILE][4];
    __shared__ int tT[MTILE];

    const int t = threadIdx.x;
    const int lane = t & 63;
    const int wv = t >> 6;
    const int quad = lane >> 4;
    const int l15 = lane & 15;
    const int sample_base = blockIdx.x * MTILE;

    // ---- phase A: load + normalize X tile into bf16 LDS ----
    {
        int row = t >> 2, part = t & 3;  // 4 threads per sample row
        const float4* src = (const float4*)(X + (size_t)(sample_base + row) * SZ_EMBED + part * 32);
        float4 r[8];
        float ss = 0.f;
        #pragma unroll
        for (int j = 0; j < 8; ++j) {
            r[j] = src[j];
            ss += r[j].x * r[j].x + r[j].y * r[j].y + r[j].z * r[j].z + r[j].w * r[j].w;
        }
        psum[row][part] = ss;
        if (t < MTILE) tT[t] = T[sample_base + t];
        __syncthreads();
        float inv = rsqrtf(psum[row][0] + psum[row][1] + psum[row][2] + psum[row][3] + 1e-12f);
        unsigned short* dst = xtile + row * XSTRIDE + part * 32;
        #pragma unroll
        for (int j = 0; j < 8; ++j) {
            uint2 pk;
            pk.x = (unsigned)f2bf(r[j].x * inv) | ((unsigned)f2bf(r[j].y * inv) << 16);
            pk.y = (unsigned)f2bf(r[j].z * inv) | ((unsigned)f2bf(r[j].w * inv) << 16);
            *(uint2*)(dst + j * 4) = pk;
        }
    }
    __syncthreads();

    // ---- hoist A fragments + labels into registers for the whole class loop ----
    v8bf afrag[4][4];
    #pragma unroll
    for (int ri = 0; ri < 4; ++ri)
        #pragma unroll
        for (int kc = 0; kc < 4; ++kc)
            afrag[ri][kc] = *(const v8bf*)(xtile + (ri * 16 + l15) * XSTRIDE + kc * 32 + quad * 8);

    int treg[16];
    #pragma unroll
    for (int ri = 0; ri < 4; ++ri) {
        int4 tv = *(const int4*)(tT + ri * 16 + quad * 4);
        treg[ri * 4 + 0] = tv.x; treg[ri * 4 + 1] = tv.y;
        treg[ri * 4 + 2] = tv.z; treg[ri * 4 + 3] = tv.w;
    }

    // ---- loop over class tiles ----
    for (int ct = 0; ct < NB_CLASSES / CTILE; ++ct) {
        __syncthreads();  // previous iter's ptile reads done
        #pragma unroll
        for (int it = 0; it < 4; ++it) {
            int chunk = t + it * 256;           // 1024 chunks of 8 bf16 (16B) = 64 rows x 128 cols
            int row = chunk >> 4, col = (chunk & 15) * 8;
            int4 v = *(const int4*)(Pn + (size_t)(ct * CTILE + row) * SZ_EMBED + col);
            *(int4*)(ptile + row * XSTRIDE + col) = v;
        }
        __syncthreads();

        v4f zero = {0.f, 0.f, 0.f, 0.f};
        v4f acc[4] = {zero, zero, zero, zero};
        #pragma unroll
        for (int kc = 0; kc < 4; ++kc) {
            v8bf b = *(const v8bf*)(ptile + (wv * 16 + l15) * XSTRIDE + kc * 32 + quad * 8);
            #pragma unroll
            for (int ri = 0; ri < 4; ++ri)
                acc[ri] = __builtin_amdgcn_mfma_f32_16x16x32_bf16(afrag[ri][kc], b, acc[ri], 0, 0, 0);
        }

        // epilogue: cos(i,c) -> exp weights -> per-class partial sums
        int cglob = ct * CTILE + wv * 16 + l15;  // C/D col = lane&15
        float pos_acc = 0.f, neg_acc = 0.f;
        #pragma unroll
        for (int ri = 0; ri < 4; ++ri) {
            #pragma unroll
            for (int r = 0; r < 4; ++r) {
                float v = acc[ri][r];            // sample = ri*16 + quad*4 + r
                bool m = (treg[ri * 4 + r] == cglob);
                float x = m ? -v : v;
                float e = exp2f(fmaf(x, EXP_A, EXP_B));
                pos_acc += m ? e : 0.f;
                neg_acc += m ? 0.f : e;
            }
        }
        pos_acc += __shfl_xor(pos_acc, 16); pos_acc += __shfl_xor(pos_acc, 32);
        neg_acc += __shfl_xor(neg_acc, 16); neg_acc += __shfl_xor(neg_acc, 32);
        if (quad == 0) {
            atomicAdd(pos_sum + cglob, pos_acc);
            atomicAdd(neg_sum + cglob, neg_acc);
        }
    }
}

__global__ __launch_bounds__(256) void finalize_kernel(
    const float* __restrict__ pos_sum, const float* __restrict__ neg_sum,
    float* __restrict__ out) {
    int t = threadIdx.x;
    float lp_pos = 0.f, lp_neg = 0.f, valid = 0.f;
    for (int c = t; c < NB_CLASSES; c += 256) {
        float ps = pos_sum[c], ns = neg_sum[c];
        lp_pos += log1pf(ps);
        lp_neg += log1pf(ns);
        valid += (ps != 0.f) ? 1.f : 0.f;
    }
    #pragma unroll
    for (int off = 32; off; off >>= 1) {
        lp_pos += __shfl_xor(lp_pos, off);
        lp_neg += __shfl_xor(lp_neg, off);
        valid  += __shfl_xor(valid, off);
    }
    __shared__ float s[3][4];
    int wv = t >> 6, lane = t & 63;
    if (lane == 0) { s[0][wv] = lp_pos; s[1][wv] = lp_neg; s[2][wv] = valid; }
    __syncthreads();
    if (t == 0) {
        float P = s[0][0] + s[0][1] + s[0][2] + s[0][3];
        float Ng = s[1][0] + s[1][1] + s[1][2] + s[1][3];
        float V = s[2][0] + s[2][1] + s[2][2] + s[2][3];
        float pos_term = (V > 0.f) ? (P / fmaxf(V, 1.f)) : 0.f;
        float neg_term = Ng / (float)NB_CLASSES;
        out[0] = pos_term + neg_term;
        out[1] = pos_term;
        out[2] = neg_term;
    }
}

extern "C" void kernel_launch(void* const* d_in, const int* in_sizes, int n_in,
                              void* d_out, int out_size, void* d_ws, size_t ws_size,
                              hipStream_t stream) {
    const float* X = (const float*)d_in[0];
    const float* proxies = (const float*)d_in[1];
    const int* T = (const int*)d_in[2];
    float* out = (float*)d_out;

    unsigned short* Pn = (unsigned short*)d_ws;
    float* pos_sum = (float*)((char*)d_ws + (size_t)NB_CLASSES * SZ_EMBED * sizeof(unsigned short));
    float* neg_sum = pos_sum + NB_CLASSES;

    hipMemsetAsync(pos_sum, 0, 2 * NB_CLASSES * sizeof(float), stream);
    norm_proxies_kernel<<<NB_CLASSES / 4, 256, 0, stream>>>(proxies, Pn);
    main_kernel<<<N_SAMPLES / MTILE, 256, 0, stream>>>(X, T, Pn, pos_sum, neg_sum);
    finalize_kernel<<<1, 256, 0, stream>>>(pos_sum, neg_sum, out);
}